// Round 11
// baseline (254.573 us; speedup 1.0000x reference)
//
#include <hip/hip_runtime.h>

typedef unsigned short ushort_t;
typedef unsigned int   uint_t;

using bf16x8 = __attribute__((ext_vector_type(8))) short;
using f32x16 = __attribute__((ext_vector_type(16))) float;

#define BATCH 16
#define CIN   64
#define COUT  64
#define LSIG  16384
#define KW    128
#define LOUT  (LSIG - KW + 1)   /* 16257 */

#define NTILE 512                /* output positions per block */
#define ROWS  640                /* NTILE + 127 halo, rounded to 16 */

__device__ __forceinline__ ushort_t f2bf(float f) {
  union { float f; uint_t u; } v; v.f = f;
  uint_t r = v.u + 0x7fffu + ((v.u >> 16) & 1u);   // RNE, matches jnp f32->bf16
  return (ushort_t)(r >> 16);
}

// ---------------- pass 1: max|w| ----------------
__global__ void k_absmax(const float* __restrict__ w, uint_t* __restrict__ amax, int n) {
  int idx = blockIdx.x * blockDim.x + threadIdx.x;
  int stride = gridDim.x * blockDim.x;
  float m = 0.f;
  for (int i = idx; i < n; i += stride) m = fmaxf(m, fabsf(w[i]));
  for (int off = 32; off > 0; off >>= 1) m = fmaxf(m, __shfl_down(m, off, 64));
  if ((threadIdx.x & 63) == 0) atomicMax(amax, __float_as_uint(m)); // positive floats: uint order == float order
}

// ---------------- pass 2: quantize + reorder weights to FRAGMENT order ----------------
// wt2[((k*8 + frag)*64 + lane)*8 + j], frag = of*4+ks, lane = hi*32+l31,
// element (o,i) = (of*32+l31, ks*16+hi*8+j).  Each A-frag load in k_conv is then one
// fully-contiguous 1KB fetch (lane*16B), and all 8 waves/CU share the same L1 lines.
__global__ void k_wprep(const float* __restrict__ w, const float* __restrict__ amaxp,
                        ushort_t* __restrict__ wt2) {
  const float scale = amaxp[0] / 127.0f;
  const int o = blockIdx.x, i = blockIdx.y, k = threadIdx.x;
  const float q = rintf(w[((size_t)o * CIN + i) * KW + k] / scale); // integer in [-127,127], exact in bf16
  const int of = o >> 5, l31 = o & 31;
  const int ks = i >> 4, hi = (i >> 3) & 1, j = i & 7;
  const int frag = of * 4 + ks, lane = hi * 32 + l31;
  wt2[(((size_t)k * 8 + frag) * 64 + lane) * 8 + j] = f2bf(q);
}

// ---------------- pass 3: signal -> sigT[b][n][i] bf16, i-block XOR-swizzled by (n&7) ----------------
__global__ void k_sprep(const float* __restrict__ sig, ushort_t* __restrict__ sigT) {
  __shared__ float tile[64][65];
  const int b = blockIdx.y;
  const int n0 = blockIdx.x * 64;
  const int t = threadIdx.x;
  {
    const int i = t >> 2, q = t & 3;
    const float4* src = (const float4*)(sig + ((size_t)(b * CIN + i)) * LSIG + n0 + q * 16);
    float4 v0 = src[0], v1 = src[1], v2 = src[2], v3 = src[3];
    float* trow = &tile[i][q * 16];
    trow[0]=v0.x; trow[1]=v0.y; trow[2]=v0.z;  trow[3]=v0.w;
    trow[4]=v1.x; trow[5]=v1.y; trow[6]=v1.z;  trow[7]=v1.w;
    trow[8]=v2.x; trow[9]=v2.y; trow[10]=v2.z; trow[11]=v2.w;
    trow[12]=v3.x; trow[13]=v3.y; trow[14]=v3.z; trow[15]=v3.w;
  }
  __syncthreads();
  const int nl = t & 63, cg = t >> 6;
  const int n = n0 + nl;
  uint_t wds[8];
#pragma unroll
  for (int p = 0; p < 8; ++p) {
    const int c0 = cg * 16 + 2 * p;
    const int c1 = c0 + 1;
    const int ia = (((c0 >> 3) ^ (n & 7)) << 3) | (c0 & 7);
    const int ib = (((c1 >> 3) ^ (n & 7)) << 3) | (c1 & 7);
    wds[p] = (uint_t)f2bf(tile[ia][nl]) | ((uint_t)f2bf(tile[ib][nl]) << 16);
  }
  uint4* dst = (uint4*)(sigT + ((size_t)b * LSIG + n) * CIN + cg * 16);
  dst[0] = make_uint4(wds[0], wds[1], wds[2], wds[3]);
  dst[1] = make_uint4(wds[4], wds[5], wds[6], wds[7]);
}

// ---------------- pass 4: the conv (implicit GEMM, 32x32x16 MFMA, uniform pipeline) ----------------
// block: 256 threads = 4 waves; each wave owns 128 output positions x all 64 Cout.
// grid = 32 x 16 = 512 blocks = exactly 2 blocks/CU (2x80KB LDS = 160KB), 8 waves/CU.
// A = weights (fragment-ordered, contiguous 1KB/load, single-buffered, reloaded
// fine-grained right after last use), B = signal from LDS, prefetch distance 2 steps.
// R11 change: WAVE PHASE SKEW. The 4 waves exit the staging barrier cycle-aligned on
// 4 SIMDs and run identical streams -> their 16-read LDS bursts flood the CU-wide LDS
// in lockstep, alternating with CU-wide droughts during the MFMA clusters (wall ~= 
// LDS + MFMA sum, not max). A startup skew of ~1/4 step-period per wave spreads the
// bursts so the LDS pipe serves one wave's reads while others are in MFMA clusters.
#define CONV_KS(KS) do {                                                               \
    { const int tpn_ = tp + (((KS) + 2) >> 2);                                         \
      const int kn_  = ((KS) + 2) & 3;                                                 \
      const int rb_  = rowbase + tpn_;                                                 \
      _Pragma("unroll") for (int nf = 0; nf < 4; ++nf) {                               \
        const int r_ = rb_ + nf * 32;                                                  \
        Bb[((KS) + 2) & 3][nf] = *(const bf16x8*)((const char*)lds + r_ * 128 +        \
                                   (((kn_ * 2 + hi) ^ (r_ & 7)) << 4));                \
      } }                                                                              \
    __builtin_amdgcn_sched_barrier(0);                                                 \
    __builtin_amdgcn_s_setprio(1);                                                     \
    _Pragma("unroll") for (int of = 0; of < 2; ++of)                                   \
      _Pragma("unroll") for (int nf = 0; nf < 4; ++nf)                                 \
        acc[of][nf] = __builtin_amdgcn_mfma_f32_32x32x16_bf16(A[of * 4 + (KS)], Bb[(KS)][nf], acc[of][nf], 0, 0, 0); \
    __builtin_amdgcn_s_setprio(0);                                                     \
    __builtin_amdgcn_sched_barrier(0);                                                 \
    { const ushort_t* pa_ = wa2 + (size_t)(tp + 1) * 4096;                             \
      _Pragma("unroll") for (int of = 0; of < 2; ++of)                                 \
        A[of * 4 + (KS)] = *(const bf16x8*)(pa_ + (of * 4 + (KS)) * 512);              \
    }                                                                                  \
    __builtin_amdgcn_sched_barrier(0);                                                 \
  } while (0)

__global__ __launch_bounds__(256, 2) void k_conv(
    const ushort_t* __restrict__ sigT, const ushort_t* __restrict__ wt2,
    const float* __restrict__ amaxp, const float* __restrict__ bias,
    float* __restrict__ out)
{
  __shared__ __align__(16) ushort_t lds[ROWS * CIN];   // 80 KB
  const int b  = blockIdx.y;
  const int n0 = blockIdx.x * NTILE;
  const int t  = threadIdx.x;
  const int wv = t >> 6;
  const int lane = t & 63;
  const int l31 = lane & 31, hi = lane >> 5;

  // stage 640 rows x 128B = one contiguous 80KB span of sigT (clamped at buffer end;
  // overrun rows only feed store-masked outputs)
  {
    const uint4* srcall = (const uint4*)sigT;
    const size_t base = ((size_t)b * LSIG + n0) * 8;       // 8 uint4 per 128B row
    const size_t lim  = (size_t)BATCH * LSIG * 8;
    uint4* dst = (uint4*)lds;
    for (int c = t; c < ROWS * 8; c += 256) {
      size_t g = base + c;
      if (g >= lim) g = lim - 1;
      dst[c] = srcall[g];
    }
  }
  __syncthreads();

  // ---- wave phase skew: ~256 cyc per wave (s_sleep sleeps imm*64 clocks) ----
  if (wv == 1)      __builtin_amdgcn_s_sleep(4);
  else if (wv == 2) __builtin_amdgcn_s_sleep(8);
  else if (wv == 3) __builtin_amdgcn_s_sleep(12);

  f32x16 acc[2][4];
#pragma unroll
  for (int i = 0; i < 2; ++i)
#pragma unroll
    for (int j = 0; j < 4; ++j)
#pragma unroll
      for (int r = 0; r < 16; ++r) acc[i][j][r] = 0.f;

  // A: fragment-ordered layout; per-lane addr = tap*4096 + frag*512 + lane*8 (ushorts)
  const ushort_t* wa2 = wt2 + (size_t)lane * 8;
  const int rowbase = wv * 128 + l31;

  bf16x8 A[8], Bb[4][4];
  // prologue: full A for tap 0; B for steps 0 (tap0,ks0) and 1 (tap0,ks1)
#pragma unroll
  for (int f = 0; f < 8; ++f) A[f] = *(const bf16x8*)(wa2 + f * 512);
#pragma unroll
  for (int nf = 0; nf < 4; ++nf) {
    const int r_ = rowbase + nf * 32;
    Bb[0][nf] = *(const bf16x8*)((const char*)lds + r_ * 128 + (((0 + hi) ^ (r_ & 7)) << 4));
    Bb[1][nf] = *(const bf16x8*)((const char*)lds + r_ * 128 + (((2 + hi) ^ (r_ & 7)) << 4));
  }

  for (int tp = 0; tp < KW; ++tp) {
    CONV_KS(0);
    CONV_KS(1);
    CONV_KS(2);
    CONV_KS(3);
  }
  // note: at tp=127 the prefetches target tap 128 — B rows stay within the 640-row
  // LDS tile (max index 639) and A reads stay inside d_ws; both values are never used.

  const float sc = amaxp[0] / 127.0f;
#pragma unroll
  for (int of = 0; of < 2; ++of) {
#pragma unroll
    for (int nf = 0; nf < 4; ++nf) {
      const int n = n0 + wv * 128 + nf * 32 + l31;
      if (n < LOUT) {
#pragma unroll
        for (int r = 0; r < 16; ++r) {
          // D: col = lane&31 (= n), row o = of*32 + 4*hi + (r&3) + 8*(r>>2)  [m74/m101 layout]
          const int o = of * 32 + 4 * hi + (r & 3) + 8 * (r >> 2);
          out[((size_t)b * COUT + o) * LOUT + n] = acc[of][nf][r] * sc + bias[o];
        }
      }
    }
  }
}

extern "C" void kernel_launch(void* const* d_in, const int* in_sizes, int n_in,
                              void* d_out, int out_size, void* d_ws, size_t ws_size,
                              hipStream_t stream) {
  const float* sig  = (const float*)d_in[0];
  const float* w    = (const float*)d_in[1];
  const float* bias = (const float*)d_in[2];
  float* out = (float*)d_out;

  // workspace layout: [0,4): amax bits | [4096, 4096+1MB+8KB slack): wt2 | [2MB, 2MB+32MB): sigT
  uint_t*   amax = (uint_t*)d_ws;
  ushort_t* wt2  = (ushort_t*)((char*)d_ws + 4096);
  ushort_t* sigT = (ushort_t*)((char*)d_ws + (size_t)(2u << 20));

  hipMemsetAsync(d_ws, 0, 4, stream);
  hipLaunchKernelGGL(k_absmax, dim3(256), dim3(256), 0, stream, w, amax, COUT * CIN * KW);
  hipLaunchKernelGGL(k_wprep, dim3(COUT, CIN), dim3(KW), 0, stream, w, (const float*)amax, wt2);
  hipLaunchKernelGGL(k_sprep, dim3(LSIG / 64, BATCH), dim3(256), 0, stream, sig, sigT);
  hipLaunchKernelGGL(k_conv, dim3((LOUT + NTILE - 1) / NTILE, BATCH), dim3(256), 0, stream,
                     sigT, wt2, (const float*)amax, bias, out);
}